// Round 1
// baseline (868.690 us; speedup 1.0000x reference)
//
#include <hip/hip_runtime.h>
#include <math.h>

#define OS    320      // oversampled grid (ceil(1.25*256))
#define IMN   256
#define NCOIL 8
#define PI_F  3.14159265358979f
#define BETA_F 10.955108f   // pi*sqrt((4.8*0.75)^2 - 0.8)

// ---- Kaiser-Bessel kernel: exact A&S I0 polynomial (matches reference) ----
__device__ __forceinline__ float i0f(float x) {
    if (x < 3.75f) {
        float y = x * (1.0f / 3.75f); y *= y;
        return 1.0f + y*(3.5156229f + y*(3.0899424f + y*(1.2067492f
             + y*(0.2659732f + y*(0.0360768f + y*0.0045813f)))));
    } else {
        float t = 3.75f / x;
        float p = 0.39894228f + t*(0.01328592f + t*(0.00225319f + t*(-0.00157565f
              + t*(0.00916281f + t*(-0.02057706f + t*(0.02635537f + t*(-0.01647633f
              + t*0.00392377f)))))));
        return expf(x) * rsqrtf(x) * p;
    }
}

__device__ __forceinline__ float kbf(float u) {
    float q = 1.0f - u * u;
    q = fmaxf(q, 0.0f);
    return i0f(BETA_F * sqrtf(q));
}

__device__ __forceinline__ float apod1(int i) {
    float idx = (float)(i - 128);
    float c = PI_F * 6.0f * idx * (1.0f / (float)OS);
    float a = sqrtf(BETA_F * BETA_F - c * c);
    float sh = 0.5f * (expf(a) - expf(-a));
    return a / sh;
}

// ---- K0: apodize + scale + centered zero-pad + ifftshift (index-folded) ----
// grid layout: [b][gy][gx], grid[n] = padded[(n+160)%320] per axis
__global__ void pad_apod_kernel(const float* __restrict__ imr,
                                const float* __restrict__ imi,
                                float2* __restrict__ grid) {
    int idx = blockIdx.x * blockDim.x + threadIdx.x;
    if (idx >= NCOIL * OS * OS) return;
    int gx = idx % OS; int r = idx / OS; int gy = r % OS; int b = r / OS;
    int my = gy + 160; if (my >= OS) my -= OS;
    int mx = gx + 160; if (mx >= OS) mx -= OS;
    int iy = my - 32, ix = mx - 32;   // pad offset py = px = 32
    float2 v = make_float2(0.f, 0.f);
    if ((unsigned)iy < 256u && (unsigned)ix < 256u) {
        float s = apod1(iy) * apod1(ix) * (1.0f / 256.0f);  // /sqrt(ny*nx)
        int ii = (b * IMN + iy) * IMN + ix;
        v.x = imr[ii] * s;
        v.y = imi[ii] * s;
    }
    grid[idx] = v;
}

// ---- K1: DFT along x for each (b, y); write transposed [b][kx][y] ----
__global__ __launch_bounds__(OS) void dft_pass1(const float2* __restrict__ in,
                                                float2* __restrict__ out) {
    __shared__ float2 xs[OS];
    __shared__ float2 tw[OS];
    int b = blockIdx.x / OS, y = blockIdx.x % OS;
    int t = threadIdx.x;
    xs[t] = in[(b * OS + y) * OS + t];
    float ang = -2.0f * PI_F * (float)t * (1.0f / (float)OS);
    tw[t] = make_float2(cosf(ang), sinf(ang));
    __syncthreads();
    float ar = 0.f, ai = 0.f;
    int idx = 0;   // (t*n) mod OS, maintained incrementally (exact)
    #pragma unroll 8
    for (int n = 0; n < OS; ++n) {
        float2 x = xs[n];
        float2 w = tw[idx];
        ar = fmaf(x.x, w.x, fmaf(-x.y, w.y, ar));
        ai = fmaf(x.x, w.y, fmaf( x.y, w.x, ai));
        idx += t; if (idx >= OS) idx -= OS;
    }
    out[(b * OS + t) * OS + y] = make_float2(ar, ai);
}

// ---- K2: DFT along y for each (b, kx); write interp layout [ky][kx][b] ----
__global__ __launch_bounds__(OS) void dft_pass2(const float2* __restrict__ in,
                                                float2* __restrict__ out) {
    __shared__ float2 xs[OS];
    __shared__ float2 tw[OS];
    int b = blockIdx.x / OS, kx = blockIdx.x % OS;
    int t = threadIdx.x;
    xs[t] = in[(b * OS + kx) * OS + t];
    float ang = -2.0f * PI_F * (float)t * (1.0f / (float)OS);
    tw[t] = make_float2(cosf(ang), sinf(ang));
    __syncthreads();
    float ar = 0.f, ai = 0.f;
    int idx = 0;
    #pragma unroll 8
    for (int n = 0; n < OS; ++n) {
        float2 x = xs[n];
        float2 w = tw[idx];
        ar = fmaf(x.x, w.x, fmaf(-x.y, w.y, ar));
        ai = fmaf(x.x, w.y, fmaf( x.y, w.x, ai));
        idx += t; if (idx >= OS) idx -= OS;
    }
    out[(t * OS + kx) * NCOIL + b] = make_float2(ar, ai);
}

// ---- K3: KB 6x6 gather at trajectory points, 8 coils per thread ----
// grid layout [ky][kx][b] (float2), so one tap = one aligned 64B line.
// fftshift folded: reference S_out[yj%320] == Fgrid[(yj+160)%320]
__global__ __launch_bounds__(256) void interp_kernel(const float* __restrict__ trj,
                                                     const float2* __restrict__ grid,
                                                     float2* __restrict__ out, int K) {
    int k = blockIdx.x * 256 + threadIdx.x;
    if (k >= K) return;
    float ty = trj[2 * k + 0], tx = trj[2 * k + 1];
    float cy = ty * 1.25f + 160.0f;   // * (oy/ny) + oy//2
    float cx = tx * 1.25f + 160.0f;
    int y0 = (int)ceilf(cy - 3.0f);
    int x0 = (int)ceilf(cx - 3.0f);
    float wy[6], wx[6]; int gy[6], gx[6];
    #pragma unroll
    for (int j = 0; j < 6; ++j) {
        float u = ((float)(y0 + j) - cy) * (1.0f / 3.0f);
        wy[j] = kbf(u);
        int yy = y0 + j + 160; if (yy >= OS) yy -= OS;  // yj+160 in [157,482]
        gy[j] = yy * OS;
        float v = ((float)(x0 + j) - cx) * (1.0f / 3.0f);
        wx[j] = kbf(v);
        int xx = x0 + j + 160; if (xx >= OS) xx -= OS;
        gx[j] = xx;
    }
    float accr[NCOIL], acci[NCOIL];
    #pragma unroll
    for (int b = 0; b < NCOIL; ++b) { accr[b] = 0.f; acci[b] = 0.f; }
    #pragma unroll
    for (int j = 0; j < 6; ++j) {
        #pragma unroll
        for (int l = 0; l < 6; ++l) {
            float w = wy[j] * wx[l];
            const float4* g = (const float4*)(grid + (size_t)(gy[j] + gx[l]) * NCOIL);
            #pragma unroll
            for (int q = 0; q < 4; ++q) {
                float4 v = g[q];
                accr[2*q]     = fmaf(w, v.x, accr[2*q]);
                acci[2*q]     = fmaf(w, v.y, acci[2*q]);
                accr[2*q + 1] = fmaf(w, v.z, accr[2*q + 1]);
                acci[2*q + 1] = fmaf(w, v.w, acci[2*q + 1]);
            }
        }
    }
    const float s = 1.0f / 36.0f;   // / WIDTH^2
    #pragma unroll
    for (int b = 0; b < NCOIL; ++b)
        out[(size_t)b * K + k] = make_float2(accr[b] * s, acci[b] * s);
}

extern "C" void kernel_launch(void* const* d_in, const int* in_sizes, int n_in,
                              void* d_out, int out_size, void* d_ws, size_t ws_size,
                              hipStream_t stream) {
    const float* imr = (const float*)d_in[0];
    const float* imi = (const float*)d_in[1];
    const float* trj = (const float*)d_in[2];
    int K = in_sizes[2] / 2;

    float2* buf0 = (float2*)d_ws;                 // [b][y][x]   6.55 MB
    float2* buf1 = buf0 + NCOIL * OS * OS;        // [b][kx][y]  6.55 MB
    float2* buf2 = buf0;                          // reuse: [ky][kx][b]

    int n主 = NCOIL * OS * OS;
    (void)n_in; (void)out_size; (void)ws_size;

    pad_apod_kernel<<<(n主 + 255) / 256, 256, 0, stream>>>(imr, imi, buf0);
    dft_pass1<<<NCOIL * OS, OS, 0, stream>>>(buf0, buf1);
    dft_pass2<<<NCOIL * OS, OS, 0, stream>>>(buf1, buf2);
    interp_kernel<<<(K + 255) / 256, 256, 0, stream>>>(trj, buf2, (float2*)d_out, K);
}

// Round 2
// 331.436 us; speedup vs baseline: 2.6210x; 2.6210x over previous
//
#include <hip/hip_runtime.h>
#include <math.h>

#define OS    320      // oversampled grid (ceil(1.25*256))
#define IMN   256
#define NCOIL 8
#define PI_F  3.14159265358979f
#define BETA_F 10.955108f   // pi*sqrt((4.8*0.75)^2 - 0.8)
#define GSCALE 65536.0f     // fp16 grid scaling (grid rms ~1e-5 -> ~0.66)

typedef _Float16 half8 __attribute__((ext_vector_type(8)));
typedef _Float16 half2v __attribute__((ext_vector_type(2)));

// ---- Kaiser-Bessel kernel: exact A&S I0 polynomial (matches reference) ----
__device__ __forceinline__ float i0f(float x) {
    if (x < 3.75f) {
        float y = x * (1.0f / 3.75f); y *= y;
        return 1.0f + y*(3.5156229f + y*(3.0899424f + y*(1.2067492f
             + y*(0.2659732f + y*(0.0360768f + y*0.0045813f)))));
    } else {
        float t = 3.75f / x;
        float p = 0.39894228f + t*(0.01328592f + t*(0.00225319f + t*(-0.00157565f
              + t*(0.00916281f + t*(-0.02057706f + t*(0.02635537f + t*(-0.01647633f
              + t*0.00392377f)))))));
        return expf(x) * rsqrtf(x) * p;
    }
}

__device__ __forceinline__ float kbf(float u) {
    float q = 1.0f - u * u;
    q = fmaxf(q, 0.0f);
    return i0f(BETA_F * sqrtf(q));
}

__device__ __forceinline__ float apod1(int i) {
    float idx = (float)(i - 128);
    float c = PI_F * 6.0f * idx * (1.0f / (float)OS);
    float a = sqrtf(BETA_F * BETA_F - c * c);
    float sh = 0.5f * (expf(a) - expf(-a));
    return a / sh;
}

// ---- K0: apodize + scale + centered zero-pad + ifftshift (index-folded) ----
// grid layout: [b][gy][gx], grid[n] = padded[(n+160)%320] per axis
__global__ void pad_apod_kernel(const float* __restrict__ imr,
                                const float* __restrict__ imi,
                                float2* __restrict__ grid) {
    int idx = blockIdx.x * blockDim.x + threadIdx.x;
    if (idx >= NCOIL * OS * OS) return;
    int gx = idx % OS; int r = idx / OS; int gy = r % OS; int b = r / OS;
    int my = gy + 160; if (my >= OS) my -= OS;
    int mx = gx + 160; if (mx >= OS) mx -= OS;
    int iy = my - 32, ix = mx - 32;   // pad offset py = px = 32
    float2 v = make_float2(0.f, 0.f);
    if ((unsigned)iy < 256u && (unsigned)ix < 256u) {
        float s = apod1(iy) * apod1(ix) * (1.0f / 256.0f);  // /sqrt(ny*nx)
        int ii = (b * IMN + iy) * IMN + ix;
        v.x = imr[ii] * s;
        v.y = imi[ii] * s;
    }
    grid[idx] = v;
}

// ---- K1: DFT along x for each (b, y); write transposed [b][kx][y] ----
__global__ __launch_bounds__(OS) void dft_pass1(const float2* __restrict__ in,
                                                float2* __restrict__ out) {
    __shared__ float2 xs[OS];
    __shared__ float2 tw[OS];
    int b = blockIdx.x / OS, y = blockIdx.x % OS;
    int t = threadIdx.x;
    xs[t] = in[(b * OS + y) * OS + t];
    float ang = -2.0f * PI_F * (float)t * (1.0f / (float)OS);
    tw[t] = make_float2(cosf(ang), sinf(ang));
    __syncthreads();
    float ar = 0.f, ai = 0.f;
    int idx = 0;   // (t*n) mod OS, maintained incrementally (exact)
    #pragma unroll 8
    for (int n = 0; n < OS; ++n) {
        float2 x = xs[n];
        float2 w = tw[idx];
        ar = fmaf(x.x, w.x, fmaf(-x.y, w.y, ar));
        ai = fmaf(x.x, w.y, fmaf( x.y, w.x, ai));
        idx += t; if (idx >= OS) idx -= OS;
    }
    out[(b * OS + t) * OS + y] = make_float2(ar, ai);
}

// ---- K2: DFT along y for each (b, kx); write fp16 interp grid [ky][kx][b] ----
// fp16 cell = 8 coils x (re,im) = 32 B; values scaled by GSCALE to stay in
// fp16 normal range (unscaled grid rms ~1e-5).
__global__ __launch_bounds__(OS) void dft_pass2(const float2* __restrict__ in,
                                                half2v* __restrict__ out) {
    __shared__ float2 xs[OS];
    __shared__ float2 tw[OS];
    int b = blockIdx.x / OS, kx = blockIdx.x % OS;
    int t = threadIdx.x;
    xs[t] = in[(b * OS + kx) * OS + t];
    float ang = -2.0f * PI_F * (float)t * (1.0f / (float)OS);
    tw[t] = make_float2(cosf(ang), sinf(ang));
    __syncthreads();
    float ar = 0.f, ai = 0.f;
    int idx = 0;
    #pragma unroll 8
    for (int n = 0; n < OS; ++n) {
        float2 x = xs[n];
        float2 w = tw[idx];
        ar = fmaf(x.x, w.x, fmaf(-x.y, w.y, ar));
        ai = fmaf(x.x, w.y, fmaf( x.y, w.x, ai));
        idx += t; if (idx >= OS) idx -= OS;
    }
    half2v h;
    h.x = (_Float16)(ar * GSCALE);
    h.y = (_Float16)(ai * GSCALE);
    out[(t * OS + kx) * NCOIL + b] = h;
}

// ---- K3: KB 6x6 gather at trajectory points, 8 coils per thread ----
// grid layout [ky][kx][b] fp16 (32 B/cell, aligned) -> L2-resident (3.28 MB).
// fftshift folded: reference S_out[yj%320] == Fgrid[(yj+160)%320]
__global__ __launch_bounds__(256) void interp_kernel(const float* __restrict__ trj,
                                                     const _Float16* __restrict__ grid,
                                                     float2* __restrict__ out, int K) {
    int k = blockIdx.x * 256 + threadIdx.x;
    if (k >= K) return;
    float ty = trj[2 * k + 0], tx = trj[2 * k + 1];
    float cy = ty * 1.25f + 160.0f;   // * (oy/ny) + oy//2
    float cx = tx * 1.25f + 160.0f;
    int y0 = (int)ceilf(cy - 3.0f);
    int x0 = (int)ceilf(cx - 3.0f);
    float wy[6], wx[6]; int gy[6], gx[6];
    #pragma unroll
    for (int j = 0; j < 6; ++j) {
        float u = ((float)(y0 + j) - cy) * (1.0f / 3.0f);
        wy[j] = kbf(u);
        int yy = y0 + j + 160; if (yy >= OS) yy -= OS;  // yj+160 in [157,482]
        gy[j] = yy * OS;
        float v = ((float)(x0 + j) - cx) * (1.0f / 3.0f);
        wx[j] = kbf(v);
        int xx = x0 + j + 160; if (xx >= OS) xx -= OS;
        gx[j] = xx;
    }
    float accr[NCOIL], acci[NCOIL];
    #pragma unroll
    for (int b = 0; b < NCOIL; ++b) { accr[b] = 0.f; acci[b] = 0.f; }
    #pragma unroll
    for (int j = 0; j < 6; ++j) {
        #pragma unroll
        for (int l = 0; l < 6; ++l) {
            float w = wy[j] * wx[l];
            const half8* g = (const half8*)(grid + (size_t)(gy[j] + gx[l]) * (NCOIL * 2));
            half8 g0 = g[0];   // coils 0-3: r,i,r,i,r,i,r,i
            half8 g1 = g[1];   // coils 4-7
            #pragma unroll
            for (int q = 0; q < 4; ++q) {
                accr[q]     = fmaf(w, (float)g0[2*q],     accr[q]);
                acci[q]     = fmaf(w, (float)g0[2*q + 1], acci[q]);
                accr[q + 4] = fmaf(w, (float)g1[2*q],     accr[q + 4]);
                acci[q + 4] = fmaf(w, (float)g1[2*q + 1], acci[q + 4]);
            }
        }
    }
    const float s = 1.0f / (36.0f * GSCALE);   // / WIDTH^2 / fp16 grid scale
    #pragma unroll
    for (int b = 0; b < NCOIL; ++b)
        out[(size_t)b * K + k] = make_float2(accr[b] * s, acci[b] * s);
}

extern "C" void kernel_launch(void* const* d_in, const int* in_sizes, int n_in,
                              void* d_out, int out_size, void* d_ws, size_t ws_size,
                              hipStream_t stream) {
    const float* imr = (const float*)d_in[0];
    const float* imi = (const float*)d_in[1];
    const float* trj = (const float*)d_in[2];
    int K = in_sizes[2] / 2;

    float2* buf0 = (float2*)d_ws;                 // [b][y][x]   6.55 MB
    float2* buf1 = buf0 + NCOIL * OS * OS;        // [b][kx][y]  6.55 MB
    _Float16* gridh = (_Float16*)buf0;            // reuse buf0: fp16 [ky][kx][b] 3.28 MB

    int ntot = NCOIL * OS * OS;
    (void)n_in; (void)out_size; (void)ws_size;

    pad_apod_kernel<<<(ntot + 255) / 256, 256, 0, stream>>>(imr, imi, buf0);
    dft_pass1<<<NCOIL * OS, OS, 0, stream>>>(buf0, buf1);
    dft_pass2<<<NCOIL * OS, OS, 0, stream>>>(buf1, (half2v*)gridh);
    interp_kernel<<<(K + 255) / 256, 256, 0, stream>>>(trj, gridh, (float2*)d_out, K);
}

// Round 3
// 205.490 us; speedup vs baseline: 4.2274x; 1.6129x over previous
//
#include <hip/hip_runtime.h>
#include <math.h>

#define OS    320      // oversampled grid (ceil(1.25*256))
#define IMN   256
#define NCOIL 8
#define PI_F  3.14159265358979f
#define BETA_F 10.955108f   // pi*sqrt((4.8*0.75)^2 - 0.8)
#define GSCALE 65536.0f     // fp16 grid scaling (grid rms ~1e-5 -> ~0.66)

typedef _Float16 half8  __attribute__((ext_vector_type(8)));
typedef _Float16 half2v __attribute__((ext_vector_type(2)));

// ---- Kaiser-Bessel kernel: exact A&S I0 polynomial (matches reference) ----
__device__ __forceinline__ float i0f(float x) {
    if (x < 3.75f) {
        float y = x * (1.0f / 3.75f); y *= y;
        return 1.0f + y*(3.5156229f + y*(3.0899424f + y*(1.2067492f
             + y*(0.2659732f + y*(0.0360768f + y*0.0045813f)))));
    } else {
        float t = 3.75f / x;
        float p = 0.39894228f + t*(0.01328592f + t*(0.00225319f + t*(-0.00157565f
              + t*(0.00916281f + t*(-0.02057706f + t*(0.02635537f + t*(-0.01647633f
              + t*0.00392377f)))))));
        return expf(x) * rsqrtf(x) * p;
    }
}

__device__ __forceinline__ float kbf(float u) {
    float q = 1.0f - u * u;
    q = fmaxf(q, 0.0f);
    return i0f(BETA_F * sqrtf(q));
}

__device__ __forceinline__ float apod1(int i) {
    float idx = (float)(i - 128);
    float c = PI_F * 6.0f * idx * (1.0f / (float)OS);
    float a = sqrtf(BETA_F * BETA_F - c * c);
    float sh = 0.5f * (expf(a) - expf(-a));
    return a / sh;
}

// ---- K0: apodize + scale + centered zero-pad + ifftshift (index-folded) ----
// output layout: [gy][gx][coil] float2; grid[n] = padded[(n+160)%320] per axis
__global__ void pad_apod_kernel(const float* __restrict__ imr,
                                const float* __restrict__ imi,
                                float2* __restrict__ g) {
    int tid = blockIdx.x * blockDim.x + threadIdx.x;
    if (tid >= OS * OS * NCOIL) return;
    int b = tid & 7; int cell = tid >> 3;
    int gx = cell % OS; int gy = cell / OS;
    int my = gy + 160; if (my >= OS) my -= OS;
    int mx = gx + 160; if (mx >= OS) mx -= OS;
    int iy = my - 32, ix = mx - 32;   // pad offset py = px = 32
    float2 v = make_float2(0.f, 0.f);
    if ((unsigned)iy < 256u && (unsigned)ix < 256u) {
        float s = apod1(iy) * apod1(ix) * (1.0f / 256.0f);  // /sqrt(ny*nx)
        int ii = (b * IMN + iy) * IMN + ix;
        v.x = imr[ii] * s;
        v.y = imi[ii] * s;
    }
    g[tid] = v;
}

// ---- K1: DFT along x, all 8 coils per block; skip the 64 all-zero columns ----
// in: [y][x][coil] float2.  out: [kx][y][coil] float2.
// Only the 256 nonzero rows y=(192+m)%320 are processed (others never read).
__global__ __launch_bounds__(320) void dft_pass1(const float2* __restrict__ in,
                                                 float2* __restrict__ out) {
    __shared__ float2 xs[256 * NCOIL];   // compact nonzero columns, 16 KB
    int my_ = blockIdx.x;                 // 0..255
    int y = my_ + 192; if (y >= OS) y -= OS;
    int t = threadIdx.x;
    const float2* row = in + (size_t)y * OS * NCOIL;
    for (int i = t; i < 256 * NCOIL; i += 320) {
        int m = i >> 3, b = i & 7;
        int n = m + 192; if (n >= OS) n -= OS;
        xs[i] = row[n * NCOIL + b];
    }
    __syncthreads();

    float ar[8], ai[8];
    #pragma unroll
    for (int b = 0; b < 8; ++b) { ar[b] = 0.f; ai[b] = 0.f; }
    int idx = (t * 192) % 320;            // (t*n) mod 320 at n=192
    float ang_t = (float)t * (-2.0f * PI_F / (float)OS);
    float wsr = cosf(ang_t), wsi = sinf(ang_t);
    float wr = 1.f, wi = 0.f;
    const float4* xv = (const float4*)xs;
    #pragma unroll 16
    for (int m = 0; m < 256; ++m) {
        if ((m & 15) == 0) {              // exact twiddle refresh
            float ang = (float)idx * (-2.0f * PI_F / (float)OS);
            wr = cosf(ang); wi = sinf(ang);
        }
        const float4* xp = xv + m * 4;
        #pragma unroll
        for (int q = 0; q < 4; ++q) {
            float4 x = xp[q];             // coils 2q, 2q+1 (broadcast read)
            ar[2*q]   = fmaf(x.x, wr, fmaf(-x.y, wi, ar[2*q]));
            ai[2*q]   = fmaf(x.x, wi, fmaf( x.y, wr, ai[2*q]));
            ar[2*q+1] = fmaf(x.z, wr, fmaf(-x.w, wi, ar[2*q+1]));
            ai[2*q+1] = fmaf(x.z, wi, fmaf( x.w, wr, ai[2*q+1]));
        }
        float nwr = fmaf(wr, wsr, -wi * wsi);
        float nwi = fmaf(wr, wsi,  wi * wsr);
        wr = nwr; wi = nwi;
        idx += t; if (idx >= OS) idx -= OS;
    }
    float4* op = (float4*)(out + ((size_t)t * OS + y) * NCOIL);  // 64B/thread
    #pragma unroll
    for (int q = 0; q < 4; ++q)
        op[q] = make_float4(ar[2*q], ai[2*q], ar[2*q+1], ai[2*q+1]);
}

// ---- K2: DFT along y, all 8 coils; write fp16 grid with fftshift folded ----
// in: [kx][y][coil] float2.  out: fp16 [ (t+160)%320 ][ (kx+160)%320 ][coil].
__global__ __launch_bounds__(320) void dft_pass2(const float2* __restrict__ in,
                                                 half2v* __restrict__ outg) {
    __shared__ float2 xs[256 * NCOIL];
    int kx = blockIdx.x;                  // 0..319
    int t = threadIdx.x;
    const float2* row = in + (size_t)kx * OS * NCOIL;
    for (int i = t; i < 256 * NCOIL; i += 320) {
        int m = i >> 3, b = i & 7;
        int n = m + 192; if (n >= OS) n -= OS;
        xs[i] = row[n * NCOIL + b];
    }
    __syncthreads();

    float ar[8], ai[8];
    #pragma unroll
    for (int b = 0; b < 8; ++b) { ar[b] = 0.f; ai[b] = 0.f; }
    int idx = (t * 192) % 320;
    float ang_t = (float)t * (-2.0f * PI_F / (float)OS);
    float wsr = cosf(ang_t), wsi = sinf(ang_t);
    float wr = 1.f, wi = 0.f;
    const float4* xv = (const float4*)xs;
    #pragma unroll 16
    for (int m = 0; m < 256; ++m) {
        if ((m & 15) == 0) {
            float ang = (float)idx * (-2.0f * PI_F / (float)OS);
            wr = cosf(ang); wi = sinf(ang);
        }
        const float4* xp = xv + m * 4;
        #pragma unroll
        for (int q = 0; q < 4; ++q) {
            float4 x = xp[q];
            ar[2*q]   = fmaf(x.x, wr, fmaf(-x.y, wi, ar[2*q]));
            ai[2*q]   = fmaf(x.x, wi, fmaf( x.y, wr, ai[2*q]));
            ar[2*q+1] = fmaf(x.z, wr, fmaf(-x.w, wi, ar[2*q+1]));
            ai[2*q+1] = fmaf(x.z, wi, fmaf( x.w, wr, ai[2*q+1]));
        }
        float nwr = fmaf(wr, wsr, -wi * wsi);
        float nwi = fmaf(wr, wsi,  wi * wsr);
        wr = nwr; wi = nwi;
        idx += t; if (idx >= OS) idx -= OS;
    }
    int r = t + 160;  if (r >= OS) r -= OS;   // fftshift fold (rows)
    int c = kx + 160; if (c >= OS) c -= OS;   // fftshift fold (cols)
    half8 h0, h1;
    #pragma unroll
    for (int q = 0; q < 4; ++q) {
        h0[2*q]   = (_Float16)(ar[q] * GSCALE);
        h0[2*q+1] = (_Float16)(ai[q] * GSCALE);
        h1[2*q]   = (_Float16)(ar[q+4] * GSCALE);
        h1[2*q+1] = (_Float16)(ai[q+4] * GSCALE);
    }
    half8* gp = (half8*)(outg + ((size_t)r * OS + c) * NCOIL);
    gp[0] = h0; gp[1] = h1;
}

// ---- K3: KB 6x6 gather; 8 coil-lanes per point (1 tx per point-tap) ----
// grid fp16 [y][x][coil] (cell 32 B); fftshift already folded into grid.
__global__ __launch_bounds__(256) void interp_kernel(const float* __restrict__ trj,
                                                     const half2v* __restrict__ g,
                                                     float2* __restrict__ out, int K) {
    int tid = blockIdx.x * 256 + threadIdx.x;
    int k = tid >> 3;          // point index
    int c = tid & 7;           // coil index (lane role)
    if (k >= K) return;
    float ty = trj[2 * k + 0], tx = trj[2 * k + 1];
    float cy = ty * 1.25f + 160.0f;   // in [0, 320)
    float cx = tx * 1.25f + 160.0f;
    int y0 = (int)ceilf(cy - 3.0f);   // in [-3, 317]
    int x0 = (int)ceilf(cx - 3.0f);

    // 12 KB weights per point, 2 kbf evals per lane, distribute via shfl
    float argu = (c < 6) ? ((float)(y0 + c) - cy) * (1.0f / 3.0f)
                         : ((float)(x0 + (c - 6)) - cx) * (1.0f / 3.0f);
    float u = kbf(argu);
    float argv = ((float)(x0 + 2 + (c & 3)) - cx) * (1.0f / 3.0f);
    float v = kbf(argv);
    int lane = threadIdx.x & 63;
    int gb = lane & 56;               // 8-lane group base within wave
    float wy0 = __shfl(u, gb + 0), wy1 = __shfl(u, gb + 1), wy2 = __shfl(u, gb + 2);
    float wy3 = __shfl(u, gb + 3), wy4 = __shfl(u, gb + 4), wy5 = __shfl(u, gb + 5);
    float wx0 = __shfl(u, gb + 6), wx1 = __shfl(u, gb + 7);
    float wx2 = __shfl(v, gb + 0), wx3 = __shfl(v, gb + 1);
    float wx4 = __shfl(v, gb + 2), wx5 = __shfl(v, gb + 3);
    float wy[6] = {wy0, wy1, wy2, wy3, wy4, wy5};
    float wx[6] = {wx0, wx1, wx2, wx3, wx4, wx5};

    int rowoff[6], coloff[6];
    #pragma unroll
    for (int j = 0; j < 6; ++j) {
        int yy = y0 + j; if (yy < 0) yy += OS; if (yy >= OS) yy -= OS;
        rowoff[j] = yy * (OS * NCOIL);
        int xx = x0 + j; if (xx < 0) xx += OS; if (xx >= OS) xx -= OS;
        coloff[j] = xx * NCOIL;
    }

    float accr = 0.f, acci = 0.f;
    #pragma unroll
    for (int j = 0; j < 6; ++j) {
        int ro = rowoff[j] + c;
        float wyj = wy[j];
        #pragma unroll
        for (int l = 0; l < 6; ++l) {
            half2v h = g[ro + coloff[l]];   // 4B/lane; 8 lanes = one 32B cell
            float w = wyj * wx[l];
            accr = fmaf(w, (float)h.x, accr);
            acci = fmaf(w, (float)h.y, acci);
        }
    }
    const float s = 1.0f / (36.0f * GSCALE);
    out[(size_t)c * K + k] = make_float2(accr * s, acci * s);
}

extern "C" void kernel_launch(void* const* d_in, const int* in_sizes, int n_in,
                              void* d_out, int out_size, void* d_ws, size_t ws_size,
                              hipStream_t stream) {
    const float* imr = (const float*)d_in[0];
    const float* imi = (const float*)d_in[1];
    const float* trj = (const float*)d_in[2];
    int K = in_sizes[2] / 2;

    float2* buf0 = (float2*)d_ws;                 // [y][x][coil]   6.55 MB
    float2* buf1 = buf0 + (size_t)OS * OS * NCOIL; // [kx][y][coil] 6.55 MB
    half2v* gridh = (half2v*)buf0;                // reuse buf0: fp16 grid 3.28 MB

    int ntot = OS * OS * NCOIL;
    (void)n_in; (void)out_size; (void)ws_size;

    pad_apod_kernel<<<(ntot + 255) / 256, 256, 0, stream>>>(imr, imi, buf0);
    dft_pass1<<<256, 320, 0, stream>>>(buf0, buf1);
    dft_pass2<<<OS, 320, 0, stream>>>(buf1, gridh);
    interp_kernel<<<(K * NCOIL + 255) / 256, 256, 0, stream>>>(trj, gridh,
                                                               (float2*)d_out, K);
}